// Round 1
// 63.871 us; speedup vs baseline: 1.0185x; 1.0185x over previous
//
#include <hip/hip_runtime.h>

// BS=32, N_IND=8 -> 256 problems; N_STEP=100, ORDER=2 -> 3x3 block-tridiagonal
// normal equations. R7: SYMMETRIC PCR — exploit C_t = B_{t-1}^T (normal equations
// are SPD block-tridiagonal; CR/PCR preserves symmetry):
//   - C is never stored/updated (was 9 regs + ~25% of upd flops)
//   - left-neighbor contribution is W = B^T A^-1 B (6) + y = B^T z (3), computed
//     BY the left lane from its own data -> shfl_up carries 9 floats (was 21)
//   - right needs G (6), Q = G B (9), z (3) -> shfl_down carries 18 (was 21)
//   - last PCR level skips Q exchange + B' update (no coupling survives s=32)
//   => ds_bpermute count 276 -> 165 per problem (-40%), the dominant serial cost
//     of this 1-wave-per-SIMD latency-bound kernel.
// Boundary handling: right side still self-annihilates via exactly-zero B blocks
// (B_L = 0 iff L > 49-s, preserved by B' = -B*Q_r). Left side uses an explicit
// (L >= s) select on W_l, y_l (replaces the old zero-C mechanism).
#define NPROB 256
#define NSTEP 100
#define T1    99

// sym 3x3 as [a00,a01,a02,a11,a12,a22]; full 3x3 row-major.
__device__ __forceinline__ void syminv3(const float A[6], float G[6]) {
    const float k00 = A[3] * A[5] - A[4] * A[4];
    const float k01 = A[2] * A[4] - A[1] * A[5];
    const float k02 = A[1] * A[4] - A[2] * A[3];
    const float det = A[0] * k00 + A[1] * k01 + A[2] * k02;
    const float id  = 1.0f / det;
    G[0] = k00 * id;
    G[1] = k01 * id;
    G[2] = k02 * id;
    G[3] = (A[0] * A[5] - A[2] * A[2]) * id;
    G[4] = (A[2] * A[1] - A[0] * A[4]) * id;
    G[5] = (A[0] * A[3] - A[1] * A[1]) * id;
}

// R = G * M (G sym)
__device__ __forceinline__ void symmul(const float G[6], const float M[9], float R[9]) {
#pragma unroll
    for (int c = 0; c < 3; ++c) {
        R[0 + c] = G[0] * M[c] + G[1] * M[3 + c] + G[2] * M[6 + c];
        R[3 + c] = G[1] * M[c] + G[3] * M[3 + c] + G[4] * M[6 + c];
        R[6 + c] = G[2] * M[c] + G[4] * M[3 + c] + G[5] * M[6 + c];
    }
}

// R = M * G (G sym)
__device__ __forceinline__ void mulsym(const float M[9], const float G[6], float R[9]) {
#pragma unroll
    for (int r = 0; r < 3; ++r) {
        R[3 * r + 0] = M[3 * r + 0] * G[0] + M[3 * r + 1] * G[1] + M[3 * r + 2] * G[2];
        R[3 * r + 1] = M[3 * r + 0] * G[1] + M[3 * r + 1] * G[3] + M[3 * r + 2] * G[4];
        R[3 * r + 2] = M[3 * r + 0] * G[2] + M[3 * r + 1] * G[4] + M[3 * r + 2] * G[5];
    }
}

__device__ __forceinline__ void symvec(const float G[6], const float v[3], float r[3]) {
    r[0] = G[0] * v[0] + G[1] * v[1] + G[2] * v[2];
    r[1] = G[1] * v[0] + G[3] * v[1] + G[4] * v[2];
    r[2] = G[2] * v[0] + G[4] * v[1] + G[5] * v[2];
}

// r = B^T v
__device__ __forceinline__ void tvec(const float B[9], const float v[3], float r[3]) {
#pragma unroll
    for (int c = 0; c < 3; ++c)
        r[c] = B[c] * v[0] + B[3 + c] * v[1] + B[6 + c] * v[2];
}

// r = B v
__device__ __forceinline__ void mvec(const float B[9], const float v[3], float r[3]) {
#pragma unroll
    for (int rr = 0; rr < 3; ++rr)
        r[rr] = B[3 * rr] * v[0] + B[3 * rr + 1] * v[1] + B[3 * rr + 2] * v[2];
}

// R = -(X * Y)
__device__ __forceinline__ void nmatmul(const float X[9], const float Y[9], float R[9]) {
#pragma unroll
    for (int r = 0; r < 3; ++r)
#pragma unroll
        for (int c = 0; c < 3; ++c)
            R[3 * r + c] = -(X[3 * r] * Y[c] + X[3 * r + 1] * Y[3 + c] + X[3 * r + 2] * Y[6 + c]);
}

// U = M * B^T, symmetric result (6)
__device__ __forceinline__ void mulbt_sym(const float M[9], const float B[9], float U[6]) {
    U[0] = M[0] * B[0] + M[1] * B[1] + M[2] * B[2];
    U[1] = M[0] * B[3] + M[1] * B[4] + M[2] * B[5];
    U[2] = M[0] * B[6] + M[1] * B[7] + M[2] * B[8];
    U[3] = M[3] * B[3] + M[4] * B[4] + M[5] * B[5];
    U[4] = M[3] * B[6] + M[4] * B[7] + M[5] * B[8];
    U[5] = M[6] * B[6] + M[7] * B[7] + M[8] * B[8];
}

// W = B^T * Q, symmetric result (6)
__device__ __forceinline__ void btq_sym(const float B[9], const float Q[9], float W[6]) {
    W[0] = B[0] * Q[0] + B[3] * Q[3] + B[6] * Q[6];
    W[1] = B[0] * Q[1] + B[3] * Q[4] + B[6] * Q[7];
    W[2] = B[0] * Q[2] + B[3] * Q[5] + B[6] * Q[8];
    W[3] = B[1] * Q[1] + B[4] * Q[4] + B[7] * Q[7];
    W[4] = B[1] * Q[2] + B[4] * Q[5] + B[7] * Q[8];
    W[5] = B[2] * Q[2] + B[5] * Q[5] + B[8] * Q[8];
}

// Build block-row t: A (sym), B (right coupling), b. C is implicit (= B_left^T).
__device__ __forceinline__ void build_sym(int t, const float* cb, const float* rb,
                                          const float* sb, const float* ivp,
                                          float A[6], float B[9], float b[3]) {
    const float c0 = cb[t * 3 + 0];
    const float c1 = cb[t * 3 + 1];
    const float c2 = cb[t * 3 + 2];
    const float r  = rb[t];
    A[0] = c0 * c0; A[1] = c0 * c1; A[2] = c0 * c2;
    A[3] = c1 * c1; A[4] = c1 * c2; A[5] = c2 * c2;
    b[0] = c0 * r;  b[1] = c1 * r;  b[2] = c2 * r;
#pragma unroll
    for (int k = 0; k < 9; ++k) B[k] = 0.0f;

    if (t == 0) {
        A[0] += 1.0f; A[3] += 1.0f;
        b[0] += ivp[0];
        b[1] += ivp[1];
    }
    if (t < T1) {  // U(h_t); B = E(h_t)^T
        const float h = sb[t], h2 = h * h;
        A[0] += 2.0f;
        A[1] += h;
        A[2] += 0.5f * h2;
        A[3] += h2 + 3.0f;
        A[4] += 0.5f * h2 * h + 1.5f * h;
        A[5] += 0.25f * h2 * h2 + 1.25f * h2;
        B[0] = -2.0f;      B[1] =  h;        B[2] = -0.5f * h2;
        B[3] = -h;         B[4] = -3.0f;     B[5] =  1.5f * h;
        B[6] = -0.5f * h2; B[7] = -1.5f * h; B[8] =  0.25f * h2;
    }
    if (t > 0) {   // V(h_{t-1}) contribution to A only (C = B_{t-1}^T implicit)
        const float hm = sb[t - 1], hm2 = hm * hm;
        A[0] += 2.0f;
        A[1] -= hm;
        A[2] += 0.5f * hm2;
        A[3] += hm2 + 3.0f;
        A[4] -= 0.5f * hm2 * hm + 1.5f * hm;
        A[5] += 0.25f * hm2 * hm2 + 1.25f * hm2;
    }
}

template <int N>
__device__ __forceinline__ void shup(const float* v, float* o, int s) {
#pragma unroll
    for (int k = 0; k < N; ++k) o[k] = __shfl_up(v[k], s, 64);
}
template <int N>
__device__ __forceinline__ void shdn(const float* v, float* o, int s) {
#pragma unroll
    for (int k = 0; k < N; ++k) o[k] = __shfl_down(v[k], s, 64);
}

__global__ __launch_bounds__(64, 1) void ode_pcr_sym_kernel(
    const float* __restrict__ coeffs,  // [256][100][3]
    const float* __restrict__ rhs,     // [256][100]
    const float* __restrict__ iv_rhs,  // [256][2]
    const float* __restrict__ steps,   // [256][99]
    float* __restrict__ out)           // u0[25600] u1[25600] u2[25600] eps[256] st[25344]
{
    const int b = blockIdx.x;
    const int L = threadIdx.x;
    const bool act = (L < 50);

    const float* cb  = coeffs + b * NSTEP * 3;
    const float* rb  = rhs    + b * NSTEP;
    const float* sb  = steps  + b * T1;
    const float* ivp = iv_rhs + b * 2;

    float Ae[6], Be[9], be[3];         // even row 2L of the 50-row system
    float Po[9], Qo[9], zo[3];         // odd-row recovery data (P = G_o C_o, Q = G_o B_o, z)
    float Wp[6], yp[3];                // fold publish: W = B_o^T G_o B_o, y = B_o^T z_o
#pragma unroll
    for (int k = 0; k < 6; ++k) { Ae[k] = 0.0f; Wp[k] = 0.0f; }
#pragma unroll
    for (int k = 0; k < 9; ++k) { Be[k] = 0.0f; Po[k] = 0.0f; Qo[k] = 0.0f; }
    be[0] = be[1] = be[2] = 0.0f;
    zo[0] = zo[1] = zo[2] = 0.0f;
    yp[0] = yp[1] = yp[2] = 0.0f;

    float U[6], Bn[9], bz[3];

    // ---------- build + CR pre-step: fold odd rows into even rows ----------
    if (act) {
        build_sym(2 * L, cb, rb, sb, ivp, Ae, Be, be);
        float Ao[6], Bo[9], bo[3];
        build_sym(2 * L + 1, cb, rb, sb, ivp, Ao, Bo, bo);

        float G[6];
        syminv3(Ao, G);
        symmul(G, Bo, Qo);     // Q_o = G_o B_o
        symvec(G, bo, zo);     // z_o = G_o b_o
        btq_sym(Bo, Qo, Wp);   // W_o = B_o^T G_o B_o   (left-publish for lane L+1)
        tvec(Bo, zo, yp);      // y_o = B_o^T z_o

        float M[9];
        mulsym(Be, G, M);      // M = B_e G_o
        // P_o = G_o C_o = G_o B_e^T = M^T (G sym)
        Po[0] = M[0]; Po[1] = M[3]; Po[2] = M[6];
        Po[3] = M[1]; Po[4] = M[4]; Po[5] = M[7];
        Po[6] = M[2]; Po[7] = M[5]; Po[8] = M[8];
        mulbt_sym(M, Be, U);   // U = B_e G_o B_e^T
        nmatmul(Be, Qo, Bn);   // B_e' = -B_e Q_o
        mvec(Be, zo, bz);      // B_e z_o
    }
    {
        float Wl[6], yl[3];
        shup<6>(Wp, Wl, 1);    // lane L-1's odd (W,y); L==0: self -> selected to 0
        shup<3>(yp, yl, 1);
        if (act) {
#pragma unroll
            for (int k = 0; k < 6; ++k) Wl[k] = (L > 0) ? Wl[k] : 0.0f;
#pragma unroll
            for (int k = 0; k < 3; ++k) yl[k] = (L > 0) ? yl[k] : 0.0f;
#pragma unroll
            for (int k = 0; k < 6; ++k) Ae[k] -= Wl[k] + U[k];
#pragma unroll
            for (int k = 0; k < 3; ++k) be[k] -= yl[k] + bz[k];
#pragma unroll
            for (int k = 0; k < 9; ++k) Be[k] = Bn[k];
        }
    }

    // ---------- 6 PCR levels on the 50-row symmetric system (s = 1..32) ----------
#pragma unroll
    for (int lv = 0; lv < 6; ++lv) {
        const int s = 1 << lv;
        const bool last = (lv == 5);   // compile-time after unroll

        float G[6] = {0, 0, 0, 0, 0, 0};
        float Q[9] = {0, 0, 0, 0, 0, 0, 0, 0, 0};
        float z[3] = {0, 0, 0};
        float W[6] = {0, 0, 0, 0, 0, 0};
        float y[3] = {0, 0, 0};
        if (act) {
            syminv3(Ae, G);
            symmul(G, Be, Q);   // Q = G B
            symvec(G, be, z);   // z = G b
            btq_sym(Be, Q, W);  // W = B^T G B
            tvec(Be, z, y);     // y = B^T z
        }
        float Wl[6], yl[3], Gr[6], zr[3], Qr[9];
        shup<6>(W, Wl, s);      // from left:  9 floats
        shup<3>(y, yl, s);
        shdn<6>(G, Gr, s);      // from right: 18 floats (9 on last level)
        shdn<3>(z, zr, s);
        if (!last) shdn<9>(Q, Qr, s);

        if (act) {
#pragma unroll
            for (int k = 0; k < 6; ++k) Wl[k] = (L >= s) ? Wl[k] : 0.0f;
#pragma unroll
            for (int k = 0; k < 3; ++k) yl[k] = (L >= s) ? yl[k] : 0.0f;

            float M[9];
            mulsym(Be, Gr, M);       // M = B G_r
            mulbt_sym(M, Be, U);     // U = B G_r B^T (0 at right boundary: B == 0)
            mvec(Be, zr, bz);        // B z_r
            if (!last) nmatmul(Be, Qr, Bn);  // B' = -B Q_r

#pragma unroll
            for (int k = 0; k < 6; ++k) Ae[k] -= Wl[k] + U[k];
#pragma unroll
            for (int k = 0; k < 3; ++k) be[k] -= yl[k] + bz[k];
            if (!last) {
#pragma unroll
                for (int k = 0; k < 9; ++k) Be[k] = Bn[k];
            }
        }
    }

    // ---------- local solve, x-exchange via shfl, odd-row recovery ----------
    float xe[3] = {0.0f, 0.0f, 0.0f};
    if (act) {
        float G[6];
        syminv3(Ae, G);
        symvec(G, be, xe);
    }
    float xr[3];
    xr[0] = __shfl_down(xe[0], 1, 64);
    xr[1] = __shfl_down(xe[1], 1, 64);
    xr[2] = __shfl_down(xe[2], 1, 64);  // L==49 reads lane 50: xe there is 0

    if (act) {
        float xo[3];
#pragma unroll
        for (int r = 0; r < 3; ++r)
            xo[r] = zo[r]
                  - (Po[3 * r] * xe[0] + Po[3 * r + 1] * xe[1] + Po[3 * r + 2] * xe[2])
                  - (Qo[3 * r] * xr[0] + Qo[3 * r + 1] * xr[1] + Qo[3 * r + 2] * xr[2]);

        const int t0 = 2 * L, t1 = 2 * L + 1;
        out[            b * NSTEP + t0] = xe[0];
        out[            b * NSTEP + t1] = xo[0];
        out[25600 +     b * NSTEP + t0] = xe[1];
        out[25600 +     b * NSTEP + t1] = xo[1];
        out[51200 +     b * NSTEP + t0] = xe[2];
        out[51200 +     b * NSTEP + t1] = xo[2];
    }

    // eps + st copy (d_out is re-poisoned before every launch)
    for (int t = L; t < T1; t += 64)
        out[77056 + b * T1 + t] = sb[t];
    if (L == 0)
        out[76800 + b] = 0.0f;
}

extern "C" void kernel_launch(void* const* d_in, const int* in_sizes, int n_in,
                              void* d_out, int out_size, void* d_ws, size_t ws_size,
                              hipStream_t stream) {
    const float* coeffs = (const float*)d_in[0];
    const float* rhs    = (const float*)d_in[1];
    const float* iv_rhs = (const float*)d_in[2];
    const float* steps  = (const float*)d_in[3];
    float* out = (float*)d_out;

    ode_pcr_sym_kernel<<<dim3(NPROB), dim3(64), 0, stream>>>(
        coeffs, rhs, iv_rhs, steps, out);
}